// Round 5
// baseline (10430.340 us; speedup 1.0000x reference)
//
#include <hip/hip_runtime.h>

#define B_  32
#define S_  512
#define E_  256
#define HD_ 256
#define NG  1024   // 4*HD
#define H_  512
#define NL  32     // num labels

typedef short bf16x8 __attribute__((ext_vector_type(8)));
typedef float f32x4  __attribute__((ext_vector_type(4)));

__device__ __forceinline__ unsigned short f2bf(float f) {
  unsigned int u = __float_as_uint(f);
  unsigned int r = u + 0x7fffu + ((u >> 16) & 1u);
  return (unsigned short)(r >> 16);
}
__device__ __forceinline__ float bf2f(unsigned short s) {
  return __uint_as_float(((unsigned int)s) << 16);
}
__device__ __forceinline__ float sigm(float x) { return 1.0f / (1.0f + __expf(-x)); }
__device__ __forceinline__ float tanh_(float x) {
  float e = __expf(2.0f * x);
  return 1.0f - 2.0f / (e + 1.0f);   // x>>0 -> 1, x<<0 -> -1
}

// ---------------------------------------------------------------- init
__global__ void init_zero(unsigned int* p, int n) {
  int i = blockIdx.x * blockDim.x + threadIdx.x;
  if (i < n) p[i] = 0u;
}

// Wp layout: [layer2][dir2][n0 32][lr 32][k 768] bf16.
// lr = g*8 + j  (g in {i,f,g,o}); global gate row = g*256 + n0*8 + j.
// k regions: [0,256)=W_hi (vs h_hi), [256,512)=W_hi (vs h_lo), [512,768)=W_lo (vs h_hi)
__global__ void init_wperm(const float* __restrict__ w0, const float* __restrict__ w1,
                           unsigned short* __restrict__ Wp) {
  int i = blockIdx.x * blockDim.x + threadIdx.x;
  const int total = 2 * 2 * 32 * 32 * 768;
  if (i >= total) return;
  int k  = i % 768;
  int lr = (i / 768) % 32;
  int n0 = (i / (768 * 32)) % 32;
  int d  = (i / (768 * 32 * 32)) % 2;
  int ly = i / (768 * 32 * 32 * 2);
  const float* w = ly ? w1 : w0;
  int grow = (lr >> 3) * 256 + n0 * 8 + (lr & 7);
  float v = w[((size_t)d * NG + grow) * HD_ + (k & 255)];
  unsigned short hi = f2bf(v);
  Wp[i] = (k < 512) ? hi : f2bf(v - bf2f(hi));
}

// ---------------------------------------------------------------- input GEMM
// C[d][m][n] = gather_A(m) . Wih[d][n][:] + bih[d][n] + bhh[d][n]
// m = b*512+t. d==1 rows use reversed-masked gather. K = 256 (l0, Asrc=emb via x) or 512 (l1, Asrc=out0).
template <int K>
__global__ __launch_bounds__(256) void gemm_gx(
    const float* __restrict__ Asrc, const int* __restrict__ x,
    const int* __restrict__ lens,
    const float* __restrict__ Wih, const float* __restrict__ bih,
    const float* __restrict__ bhh, float* __restrict__ gx) {
  __shared__ __align__(16) float As[16][128];
  __shared__ __align__(16) float Ws[16][128];
  __shared__ const float* rowp[128];
  const int tid = threadIdx.x;
  const int d  = blockIdx.z;
  const int n0 = blockIdx.x * 128;
  const int m0 = blockIdx.y * 128;
  if (tid < 128) {
    int m = m0 + tid;
    int b = m >> 9, t = m & 511;
    const float* p = nullptr;
    if (d == 0) {
      p = x ? (Asrc + (size_t)x[b * S_ + t] * K) : (Asrc + ((size_t)b * S_ + t) * K);
    } else {
      int Lb = lens[b];
      if (t < Lb) {
        int src = Lb - 1 - t;
        p = x ? (Asrc + (size_t)x[b * S_ + src] * K) : (Asrc + ((size_t)b * S_ + src) * K);
      }  // else: zero row (reverse_padded masks to 0)
    }
    rowp[tid] = p;
  }
  __syncthreads();
  const float* wb = Wih + (size_t)d * NG * K + (size_t)n0 * K;
  float acc[8][8];
#pragma unroll
  for (int i = 0; i < 8; ++i)
#pragma unroll
    for (int j = 0; j < 8; ++j) acc[i][j] = 0.0f;
  const int lr = tid >> 1;
  const int kq = (tid & 1) * 8;
  const int ty = tid >> 4, tx = tid & 15;
  for (int k0 = 0; k0 < K; k0 += 16) {
    const float* pa = rowp[lr];
    float4 a0 = make_float4(0.f, 0.f, 0.f, 0.f), a1 = a0;
    if (pa) {
      a0 = *(const float4*)(pa + k0 + kq);
      a1 = *(const float4*)(pa + k0 + kq + 4);
    }
    const float* pw = wb + (size_t)lr * K + k0 + kq;
    float4 w0v = *(const float4*)pw;
    float4 w1v = *(const float4*)(pw + 4);
    if (k0) __syncthreads();
    As[kq + 0][lr] = a0.x; As[kq + 1][lr] = a0.y; As[kq + 2][lr] = a0.z; As[kq + 3][lr] = a0.w;
    As[kq + 4][lr] = a1.x; As[kq + 5][lr] = a1.y; As[kq + 6][lr] = a1.z; As[kq + 7][lr] = a1.w;
    Ws[kq + 0][lr] = w0v.x; Ws[kq + 1][lr] = w0v.y; Ws[kq + 2][lr] = w0v.z; Ws[kq + 3][lr] = w0v.w;
    Ws[kq + 4][lr] = w1v.x; Ws[kq + 5][lr] = w1v.y; Ws[kq + 6][lr] = w1v.z; Ws[kq + 7][lr] = w1v.w;
    __syncthreads();
#pragma unroll
    for (int kk = 0; kk < 16; ++kk) {
      float4 av0 = *(const float4*)&As[kk][ty * 8];
      float4 av1 = *(const float4*)&As[kk][ty * 8 + 4];
      float4 wv0 = *(const float4*)&Ws[kk][tx * 8];
      float4 wv1 = *(const float4*)&Ws[kk][tx * 8 + 4];
      float av[8] = {av0.x, av0.y, av0.z, av0.w, av1.x, av1.y, av1.z, av1.w};
      float wv[8] = {wv0.x, wv0.y, wv0.z, wv0.w, wv1.x, wv1.y, wv1.z, wv1.w};
#pragma unroll
      for (int i = 0; i < 8; ++i)
#pragma unroll
        for (int j = 0; j < 8; ++j) acc[i][j] = __fmaf_rn(av[i], wv[j], acc[i][j]);
    }
  }
  float bj[8];
#pragma unroll
  for (int j = 0; j < 8; ++j) {
    int col = n0 + tx * 8 + j;
    bj[j] = bih[d * NG + col] + bhh[d * NG + col];
  }
#pragma unroll
  for (int i = 0; i < 8; ++i) {
    int m = m0 + ty * 8 + i;
    float* dst = gx + ((size_t)d * 16384 + m) * NG + n0 + tx * 8;
    float4 o0 = make_float4(acc[i][0] + bj[0], acc[i][1] + bj[1], acc[i][2] + bj[2], acc[i][3] + bj[3]);
    float4 o1 = make_float4(acc[i][4] + bj[4], acc[i][5] + bj[5], acc[i][6] + bj[6], acc[i][7] + bj[7]);
    *(float4*)dst = o0;
    *(float4*)(dst + 4) = o1;
  }
}

// ---------------------------------------------------------------- recurrent LSTM (both dirs)
// grid = 256 blocks x 64 threads; only blockIdx%8 in {0,1} work (dir = that value, n0 = bx>>3).
// With round-robin block->XCD dispatch this co-locates each direction's 32 workers on one XCD
// (shared L2 for h broadcast + gx stream) — perf heuristic only; correctness is placement-
// independent (agent-scope sync). hbuf layout is PRODUCER-EXCLUSIVE: [dir][parity][n0][hi/lo]
// [batch 32][8 units] so each producer owns line-exclusive 1KB (no false sharing). Flags are
// padded to one cacheline (16 dwords) per producer.
__global__ __launch_bounds__(64, 1) void lstm_rec(
    const float* __restrict__ gx,          // [2][16384][1024]
    const unsigned short* __restrict__ Wp, // this layer: [2][32][32][768]
    const int* __restrict__ lens,
    unsigned short* hbuf,                  // this layer: [dir2][parity2][n0 32][reg2][b32][u8]
    unsigned int* flags,                   // this layer: [dir2][n0 32][16]  (64B-padded)
    float* __restrict__ out) {             // [32][512][512]
  const int bx = blockIdx.x;
  if ((bx & 7) >= 2) return;               // idle filler blocks (XCD co-location heuristic)
  const int d  = bx & 7;
  const int n0 = bx >> 3;
  const int lane = threadIdx.x;
  const int c15  = lane & 15;
  const int kgrp = lane >> 4;  // 0..3
  // resident B fragments: bf[nt][ks], nt: local rows nt*16..+15, ks: K-step of 32
  bf16x8 bf[2][24];
  {
    const unsigned short* wp = Wp + ((size_t)(d * 32 + n0)) * 32 * 768;
#pragma unroll
    for (int nt = 0; nt < 2; ++nt)
#pragma unroll
      for (int ks = 0; ks < 24; ++ks) {
        int lrr = nt * 16 + c15;
        int k = ks * 32 + kgrp * 8;
        bf[nt][ks] = *(const bf16x8*)(wp + (size_t)lrr * 768 + k);
      }
  }
  unsigned short* hb = hbuf + (size_t)d * 32768;   // 2 parities x 16384 shorts
  unsigned int* fl = flags + d * 512;              // 32 producers x 16 dwords
  const float* gxd = gx + (size_t)d * 16384 * NG;
  const int ue = n0 * 8 + (lane & 7);
  const bool writer = ((lane & 8) == 0);
  float cst[8], hold[8];
  int Le[8];
#pragma unroll
  for (int i = 0; i < 8; ++i) { cst[i] = 0.f; hold[i] = 0.f; }
#pragma unroll
  for (int mt = 0; mt < 2; ++mt)
#pragma unroll
    for (int r = 0; r < 4; ++r) Le[mt * 4 + r] = lens[mt * 16 + kgrp * 4 + r];

  for (int s = 0; s < S_; ++s) {
    // acc init = gx (prefetched before the spin; C-frag layout: row=batch=(kgrp*4+r), col=c15)
    f32x4 acc[2][2];
#pragma unroll
    for (int mt = 0; mt < 2; ++mt)
#pragma unroll
      for (int nt = 0; nt < 2; ++nt) {
        int grow = (nt * 2 + (c15 >> 3)) * 256 + n0 * 8 + (c15 & 7);
#pragma unroll
        for (int r = 0; r < 4; ++r) {
          int bb = mt * 16 + kgrp * 4 + r;
          acc[mt][nt][r] = gxd[((size_t)bb * S_ + s) * NG + grow];
        }
      }
    // wait for h_{s-1}: all 32 producer flags >= s
    if (s > 0) {
      const unsigned int target = (unsigned int)s;
      while (true) {
        unsigned int v = __hip_atomic_load(&fl[(lane & 31) * 16], __ATOMIC_RELAXED, __HIP_MEMORY_SCOPE_AGENT);
        if (__all(v >= target)) break;
        __builtin_amdgcn_s_sleep(1);
      }
      unsigned int v = __hip_atomic_load(&fl[(lane & 31) * 16], __ATOMIC_ACQUIRE, __HIP_MEMORY_SCOPE_AGENT);
      asm volatile("" ::"v"(v));  // keep the acquire
    }
    const unsigned short* hr = hb + ((s + 1) & 1) * 16384;
    // ks 0..7: A = h_hi (producer chunk ks*4+kgrp, reg 0), B regions 0 (W_hi) and 2 (W_lo)
#pragma unroll
    for (int ks = 0; ks < 8; ++ks) {
      const unsigned short* pa = hr + ((ks * 4 + kgrp) << 9);
      bf16x8 a0 = *(const bf16x8*)(pa + c15 * 8);
      bf16x8 a1 = *(const bf16x8*)(pa + (c15 + 16) * 8);
      acc[0][0] = __builtin_amdgcn_mfma_f32_16x16x32_bf16(a0, bf[0][ks], acc[0][0], 0, 0, 0);
      acc[0][1] = __builtin_amdgcn_mfma_f32_16x16x32_bf16(a0, bf[1][ks], acc[0][1], 0, 0, 0);
      acc[1][0] = __builtin_amdgcn_mfma_f32_16x16x32_bf16(a1, bf[0][ks], acc[1][0], 0, 0, 0);
      acc[1][1] = __builtin_amdgcn_mfma_f32_16x16x32_bf16(a1, bf[1][ks], acc[1][1], 0, 0, 0);
      acc[0][0] = __builtin_amdgcn_mfma_f32_16x16x32_bf16(a0, bf[0][ks + 16], acc[0][0], 0, 0, 0);
      acc[0][1] = __builtin_amdgcn_mfma_f32_16x16x32_bf16(a0, bf[1][ks + 16], acc[0][1], 0, 0, 0);
      acc[1][0] = __builtin_amdgcn_mfma_f32_16x16x32_bf16(a1, bf[0][ks + 16], acc[1][0], 0, 0, 0);
      acc[1][1] = __builtin_amdgcn_mfma_f32_16x16x32_bf16(a1, bf[1][ks + 16], acc[1][1], 0, 0, 0);
    }
    // ks 8..15: A = h_lo (producer chunk (ks-8)*4+kgrp, reg 1), B region 1 (W_hi)
#pragma unroll
    for (int ks = 8; ks < 16; ++ks) {
      const unsigned short* pa = hr + (((ks - 8) * 4 + kgrp) << 9) + 256;
      bf16x8 a0 = *(const bf16x8*)(pa + c15 * 8);
      bf16x8 a1 = *(const bf16x8*)(pa + (c15 + 16) * 8);
      acc[0][0] = __builtin_amdgcn_mfma_f32_16x16x32_bf16(a0, bf[0][ks], acc[0][0], 0, 0, 0);
      acc[0][1] = __builtin_amdgcn_mfma_f32_16x16x32_bf16(a0, bf[1][ks], acc[0][1], 0, 0, 0);
      acc[1][0] = __builtin_amdgcn_mfma_f32_16x16x32_bf16(a1, bf[0][ks], acc[1][0], 0, 0, 0);
      acc[1][1] = __builtin_amdgcn_mfma_f32_16x16x32_bf16(a1, bf[1][ks], acc[1][1], 0, 0, 0);
    }
    // epilogue: nt0 cols = [i(0..7), f(0..7)], nt1 cols = [g(0..7), o(0..7)]
    unsigned short* hw = hb + (s & 1) * 16384 + n0 * 512;  // this producer's exclusive 1KB
    float outv_[8];
    int   opos_[8];
#pragma unroll
    for (int mt = 0; mt < 2; ++mt)
#pragma unroll
      for (int r = 0; r < 4; ++r) {
        const int idx = mt * 4 + r;
        float x0 = acc[mt][0][r];
        float y0 = __shfl_xor(x0, 8);
        float x1 = acc[mt][1][r];
        float y1 = __shfl_xor(x1, 8);
        float iv = (lane & 8) ? y0 : x0;
        float fv = (lane & 8) ? x0 : y0;
        float gv = (lane & 8) ? y1 : x1;
        float ov = (lane & 8) ? x1 : y1;
        iv = sigm(iv); fv = sigm(fv); gv = tanh_(gv); ov = sigm(ov);
        bool act = (s < Le[idx]);
        float cn = fv * cst[idx] + iv * gv;
        float hn = ov * tanh_(cn);
        if (act) { cst[idx] = cn; hold[idx] = hn; }
        if (writer) {
          int bb = mt * 16 + kgrp * 4 + r;
          float hcur = hold[idx];
          unsigned short hi = f2bf(hcur);
          unsigned short lo = f2bf(hcur - bf2f(hi));
          __hip_atomic_store(&hw[bb * 8 + (lane & 7)], hi, __ATOMIC_RELAXED, __HIP_MEMORY_SCOPE_AGENT);
          __hip_atomic_store(&hw[256 + bb * 8 + (lane & 7)], lo, __ATOMIC_RELAXED, __HIP_MEMORY_SCOPE_AGENT);
          opos_[idx] = act ? (d == 0 ? s : (Le[idx] - 1 - s)) : s;
          outv_[idx] = act ? hn : 0.f;
        }
      }
    // release: h stores drained, then this producer's padded flag (relaxed, no RMW)
    asm volatile("s_waitcnt vmcnt(0)" ::: "memory");
    if (lane == 0)
      __hip_atomic_store(&fl[n0 * 16], (unsigned int)(s + 1), __ATOMIC_RELAXED, __HIP_MEMORY_SCOPE_AGENT);
    // out[] stores AFTER the flag — off the sync critical path, drain during next spin
    if (writer) {
#pragma unroll
      for (int mt = 0; mt < 2; ++mt)
#pragma unroll
        for (int r = 0; r < 4; ++r) {
          const int idx = mt * 4 + r;
          int bb = mt * 16 + kgrp * 4 + r;
          out[((size_t)bb * S_ + opos_[idx]) * H_ + d * HD_ + ue] = outv_[idx];
        }
    }
  }
}

// ---------------------------------------------------------------- dense (emissions)
__global__ __launch_bounds__(256) void dense_em(const float* __restrict__ h,
                                                const float* __restrict__ W,
                                                const float* __restrict__ bias,
                                                float* __restrict__ em) {
  const int tid = threadIdx.x;
  const int n = tid & 31, rg = tid >> 5;  // 8 row groups
  const int m0 = blockIdx.x * 16;
  const int r0 = m0 + rg, r1 = m0 + rg + 8;
  const float4* h0 = (const float4*)(h + (size_t)r0 * H_);
  const float4* h1 = (const float4*)(h + (size_t)r1 * H_);
  const float4* wn = (const float4*)(W + (size_t)n * H_);
  float a0 = 0.f, a1 = 0.f;
  for (int k4 = 0; k4 < 128; ++k4) {
    float4 w = wn[k4];
    float4 v0 = h0[k4];
    float4 v1 = h1[k4];
    a0 += v0.x * w.x + v0.y * w.y + v0.z * w.z + v0.w * w.w;
    a1 += v1.x * w.x + v1.y * w.y + v1.z * w.z + v1.w * w.w;
  }
  float bb = bias[n];
  em[(size_t)r0 * NL + n] = a0 + bb;
  em[(size_t)r1 * NL + n] = a1 + bb;
}

// ---------------------------------------------------------------- viterbi
__global__ __launch_bounds__(64) void viterbi(const float* __restrict__ em,
                                              const int* __restrict__ lens,
                                              const float* __restrict__ tr,
                                              const float* __restrict__ st,
                                              const float* __restrict__ et,
                                              float* __restrict__ tags,
                                              float* __restrict__ scores) {
  __shared__ unsigned char bp[512][32];
  const int b = blockIdx.x;
  const int lane = threadIdx.x;
  const int j = lane & 31;
  const int Lb = lens[b];
  const float* eb = em + (size_t)b * S_ * NL;
  float tc[32];
#pragma unroll
  for (int i = 0; i < 32; ++i) tc[i] = tr[i * 32 + j];
  float alpha = st[j] + eb[j];
  for (int t = 1; t < Lb; ++t) {
    float m = -3.4e38f;
    int mi = 0;
#pragma unroll
    for (int i = 0; i < 32; ++i) {
      float v = __shfl(alpha, i, 64) + tc[i];
      if (v > m) { m = v; mi = i; }   // strict > : first max wins (np.argmax)
    }
    if (lane < 32) bp[t][j] = (unsigned char)mi;
    alpha = m + eb[t * NL + j];
  }
  float fin = alpha + et[j];
  float m = -3.4e38f;
  int mi = 0;
#pragma unroll
  for (int i = 0; i < 32; ++i) {
    float v = __shfl(fin, i, 64);
    if (v > m) { m = v; mi = i; }
  }
  __syncthreads();  // bp visible to lane 0
  if (lane == 0) {
    scores[b] = m;
    int cur = mi;
    for (int t = Lb - 1; t >= 1; --t) {
      tags[(size_t)b * S_ + t] = (float)cur;
      cur = bp[t][cur];
    }
    tags[(size_t)b * S_] = (float)cur;
  }
  for (int t = Lb + lane; t < S_; t += 64) tags[(size_t)b * S_ + t] = 0.f;
}

// ---------------------------------------------------------------- launch
extern "C" void kernel_launch(void* const* d_in, const int* in_sizes, int n_in,
                              void* d_out, int out_size, void* d_ws, size_t ws_size,
                              hipStream_t stream) {
  const int*   x     = (const int*)d_in[0];
  const int*   xlen  = (const int*)d_in[1];
  const float* emb   = (const float*)d_in[2];
  const float* w_ih0 = (const float*)d_in[3];
  const float* w_hh0 = (const float*)d_in[4];
  const float* b_ih0 = (const float*)d_in[5];
  const float* b_hh0 = (const float*)d_in[6];
  const float* w_ih1 = (const float*)d_in[7];
  const float* w_hh1 = (const float*)d_in[8];
  const float* b_ih1 = (const float*)d_in[9];
  const float* b_hh1 = (const float*)d_in[10];
  const float* dw    = (const float*)d_in[11];
  const float* db    = (const float*)d_in[12];
  const float* tr    = (const float*)d_in[13];
  const float* st    = (const float*)d_in[14];
  const float* et    = (const float*)d_in[15];

  char* ws = (char*)d_ws;
  // ws layout (bytes): gx 128MB | out0 32MB | out1 32MB | Wp 6MB | hbuf 256KB (2 layers) | flags 8KB
  float*          gx    = (float*)(ws);
  float*          out0  = (float*)(ws + 134217728);
  float*          out1  = (float*)(ws + 167772160);
  unsigned short* Wp    = (unsigned short*)(ws + 201326592);
  unsigned short* hbuf  = (unsigned short*)(ws + 207618048);
  unsigned int*   flags = (unsigned int*)(ws + 207880192);  // = hbuf + 262144B (contiguous)

  float* emis   = (float*)d_out;          // [32][512][32]
  float* tags   = emis + 524288;          // [32][512]
  float* scores = tags + 16384;           // [32]

  // zero hbuf (2 layers x 128KB = 65536 u32) + flags (2 layers x 1024 u32) — contiguous
  init_zero<<<264, 256, 0, stream>>>((unsigned int*)hbuf, 67584);
  init_wperm<<<12288, 256, 0, stream>>>(w_hh0, w_hh1, Wp);

  // layer 0
  gemm_gx<256><<<dim3(8, 128, 2), 256, 0, stream>>>(emb, x, xlen, w_ih0, b_ih0, b_hh0, gx);
  lstm_rec<<<256, 64, 0, stream>>>(gx, Wp, xlen, hbuf, flags, out0);
  // layer 1
  gemm_gx<512><<<dim3(8, 128, 2), 256, 0, stream>>>(out0, nullptr, xlen, w_ih1, b_ih1, b_hh1, gx);
  lstm_rec<<<256, 64, 0, stream>>>(gx, Wp + 1572864, xlen, hbuf + 65536, flags + 1024, out1);
  // emissions + CRF decode
  dense_em<<<1024, 256, 0, stream>>>(out1, dw, db, emis);
  viterbi<<<32, 64, 0, stream>>>(emis, xlen, tr, st, et, tags, scores);
}

// Round 6
// 6839.601 us; speedup vs baseline: 1.5250x; 1.5250x over previous
//
#include <hip/hip_runtime.h>

#define B_  32
#define S_  512
#define E_  256
#define HD_ 256
#define NG  1024   // 4*HD
#define H_  512
#define NL  32     // num labels

typedef short bf16x8 __attribute__((ext_vector_type(8)));
typedef float f32x4  __attribute__((ext_vector_type(4)));

__device__ __forceinline__ unsigned short f2bf(float f) {
  unsigned int u = __float_as_uint(f);
  unsigned int r = u + 0x7fffu + ((u >> 16) & 1u);
  return (unsigned short)(r >> 16);
}
__device__ __forceinline__ float bf2f(unsigned short s) {
  return __uint_as_float(((unsigned int)s) << 16);
}
__device__ __forceinline__ float sigm(float x) { return 1.0f / (1.0f + __expf(-x)); }
__device__ __forceinline__ float tanh_(float x) {
  float e = __expf(2.0f * x);
  return 1.0f - 2.0f / (e + 1.0f);   // x>>0 -> 1, x<<0 -> -1
}

// ---------------------------------------------------------------- init
__global__ void init_zero(unsigned int* p, int n) {
  int i = blockIdx.x * blockDim.x + threadIdx.x;
  if (i < n) p[i] = 0u;
}

// Wp layout: [layer2][dir2][n0 32][lr 32][k 768] bf16.
// lr = g*8 + j  (g in {i,f,g,o}); global gate row = g*256 + n0*8 + j.
// k regions: [0,256)=W_hi (vs h_hi), [256,512)=W_hi (vs h_lo), [512,768)=W_lo (vs h_hi)
__global__ void init_wperm(const float* __restrict__ w0, const float* __restrict__ w1,
                           unsigned short* __restrict__ Wp) {
  int i = blockIdx.x * blockDim.x + threadIdx.x;
  const int total = 2 * 2 * 32 * 32 * 768;
  if (i >= total) return;
  int k  = i % 768;
  int lr = (i / 768) % 32;
  int n0 = (i / (768 * 32)) % 32;
  int d  = (i / (768 * 32 * 32)) % 2;
  int ly = i / (768 * 32 * 32 * 2);
  const float* w = ly ? w1 : w0;
  int grow = (lr >> 3) * 256 + n0 * 8 + (lr & 7);
  float v = w[((size_t)d * NG + grow) * HD_ + (k & 255)];
  unsigned short hi = f2bf(v);
  Wp[i] = (k < 512) ? hi : f2bf(v - bf2f(hi));
}

// ---------------------------------------------------------------- input GEMM
template <int K>
__global__ __launch_bounds__(256) void gemm_gx(
    const float* __restrict__ Asrc, const int* __restrict__ x,
    const int* __restrict__ lens,
    const float* __restrict__ Wih, const float* __restrict__ bih,
    const float* __restrict__ bhh, float* __restrict__ gx) {
  __shared__ __align__(16) float As[16][128];
  __shared__ __align__(16) float Ws[16][128];
  __shared__ const float* rowp[128];
  const int tid = threadIdx.x;
  const int d  = blockIdx.z;
  const int n0 = blockIdx.x * 128;
  const int m0 = blockIdx.y * 128;
  if (tid < 128) {
    int m = m0 + tid;
    int b = m >> 9, t = m & 511;
    const float* p = nullptr;
    if (d == 0) {
      p = x ? (Asrc + (size_t)x[b * S_ + t] * K) : (Asrc + ((size_t)b * S_ + t) * K);
    } else {
      int Lb = lens[b];
      if (t < Lb) {
        int src = Lb - 1 - t;
        p = x ? (Asrc + (size_t)x[b * S_ + src] * K) : (Asrc + ((size_t)b * S_ + src) * K);
      }  // else: zero row (reverse_padded masks to 0)
    }
    rowp[tid] = p;
  }
  __syncthreads();
  const float* wb = Wih + (size_t)d * NG * K + (size_t)n0 * K;
  float acc[8][8];
#pragma unroll
  for (int i = 0; i < 8; ++i)
#pragma unroll
    for (int j = 0; j < 8; ++j) acc[i][j] = 0.0f;
  const int lr = tid >> 1;
  const int kq = (tid & 1) * 8;
  const int ty = tid >> 4, tx = tid & 15;
  for (int k0 = 0; k0 < K; k0 += 16) {
    const float* pa = rowp[lr];
    float4 a0 = make_float4(0.f, 0.f, 0.f, 0.f), a1 = a0;
    if (pa) {
      a0 = *(const float4*)(pa + k0 + kq);
      a1 = *(const float4*)(pa + k0 + kq + 4);
    }
    const float* pw = wb + (size_t)lr * K + k0 + kq;
    float4 w0v = *(const float4*)pw;
    float4 w1v = *(const float4*)(pw + 4);
    if (k0) __syncthreads();
    As[kq + 0][lr] = a0.x; As[kq + 1][lr] = a0.y; As[kq + 2][lr] = a0.z; As[kq + 3][lr] = a0.w;
    As[kq + 4][lr] = a1.x; As[kq + 5][lr] = a1.y; As[kq + 6][lr] = a1.z; As[kq + 7][lr] = a1.w;
    Ws[kq + 0][lr] = w0v.x; Ws[kq + 1][lr] = w0v.y; Ws[kq + 2][lr] = w0v.z; Ws[kq + 3][lr] = w0v.w;
    Ws[kq + 4][lr] = w1v.x; Ws[kq + 5][lr] = w1v.y; Ws[kq + 6][lr] = w1v.z; Ws[kq + 7][lr] = w1v.w;
    __syncthreads();
#pragma unroll
    for (int kk = 0; kk < 16; ++kk) {
      float4 av0 = *(const float4*)&As[kk][ty * 8];
      float4 av1 = *(const float4*)&As[kk][ty * 8 + 4];
      float4 wv0 = *(const float4*)&Ws[kk][tx * 8];
      float4 wv1 = *(const float4*)&Ws[kk][tx * 8 + 4];
      float av[8] = {av0.x, av0.y, av0.z, av0.w, av1.x, av1.y, av1.z, av1.w};
      float wv[8] = {wv0.x, wv0.y, wv0.z, wv0.w, wv1.x, wv1.y, wv1.z, wv1.w};
#pragma unroll
      for (int i = 0; i < 8; ++i)
#pragma unroll
        for (int j = 0; j < 8; ++j) acc[i][j] = __fmaf_rn(av[i], wv[j], acc[i][j]);
    }
  }
  float bj[8];
#pragma unroll
  for (int j = 0; j < 8; ++j) {
    int col = n0 + tx * 8 + j;
    bj[j] = bih[d * NG + col] + bhh[d * NG + col];
  }
#pragma unroll
  for (int i = 0; i < 8; ++i) {
    int m = m0 + ty * 8 + i;
    float* dst = gx + ((size_t)d * 16384 + m) * NG + n0 + tx * 8;
    float4 o0 = make_float4(acc[i][0] + bj[0], acc[i][1] + bj[1], acc[i][2] + bj[2], acc[i][3] + bj[3]);
    float4 o1 = make_float4(acc[i][4] + bj[4], acc[i][5] + bj[5], acc[i][6] + bj[6], acc[i][7] + bj[7]);
    *(float4*)dst = o0;
    *(float4*)(dst + 4) = o1;
  }
}

// ---------------------------------------------------------------- recurrent LSTM (both dirs)
// 64 blocks x 64 threads (spread over all XCDs — R5 colocation reverted: it funneled all MALL
// traffic through one XCD port). Block (d=bx>>5, n0=bx&31) owns units [n0*8, n0*8+8) for all 32
// batches of dir d. NO acquire/buffer_inv anywhere: consumer reads h via relaxed AGENT-scope
// atomic u64 loads (MALL-direct, bypass stale L1/L2) — valid because producer drains vmcnt(0)
// BEFORE its canary flag store, so flag-visible => data-at-MALL. gx/Wp stay cached all 512 steps.
// hbuf producer-exclusive: [dir][parity][n0][reg2][b32][u8]; flags padded 64B/producer.
__global__ __launch_bounds__(64, 1) void lstm_rec(
    const float* __restrict__ gx,          // [2][16384][1024]
    const unsigned short* __restrict__ Wp, // this layer: [2][32][32][768]
    const int* __restrict__ lens,
    unsigned short* hbuf,                  // this layer: [dir2][parity2][n0 32][reg2][b32][u8]
    unsigned int* flags,                   // this layer: [dir2][n0 32][16]  (64B-padded)
    float* __restrict__ out) {             // [32][512][512]
  const int lane = threadIdx.x;
  const int d    = blockIdx.x >> 5;
  const int n0   = blockIdx.x & 31;
  const int c15  = lane & 15;
  const int kgrp = lane >> 4;  // 0..3
  // resident B fragments: bf[nt][ks], nt: local rows nt*16..+15, ks: K-step of 32
  bf16x8 bf[2][24];
  {
    const unsigned short* wp = Wp + ((size_t)(d * 32 + n0)) * 32 * 768;
#pragma unroll
    for (int nt = 0; nt < 2; ++nt)
#pragma unroll
      for (int ks = 0; ks < 24; ++ks) {
        int lrr = nt * 16 + c15;
        int k = ks * 32 + kgrp * 8;
        bf[nt][ks] = *(const bf16x8*)(wp + (size_t)lrr * 768 + k);
      }
  }
  unsigned short* hb = hbuf + (size_t)d * 32768;   // 2 parities x 16384 shorts
  unsigned int* fl = flags + d * 512;              // 32 producers x 16 dwords
  const float* gxd = gx + (size_t)d * 16384 * NG;
  const int ue = n0 * 8 + (lane & 7);
  const bool writer = ((lane & 8) == 0);
  float cst[8], hold[8];
  int Le[8];
#pragma unroll
  for (int i = 0; i < 8; ++i) { cst[i] = 0.f; hold[i] = 0.f; }
#pragma unroll
  for (int mt = 0; mt < 2; ++mt)
#pragma unroll
    for (int r = 0; r < 4; ++r) Le[mt * 4 + r] = lens[mt * 16 + kgrp * 4 + r];

  union U2 { unsigned long long q[2]; bf16x8 v; };

  for (int s = 0; s < S_; ++s) {
    // acc init = gx (prefetched before the spin; C-frag layout: row=batch=(kgrp*4+r), col=c15)
    f32x4 acc[2][2];
#pragma unroll
    for (int mt = 0; mt < 2; ++mt)
#pragma unroll
      for (int nt = 0; nt < 2; ++nt) {
        int grow = (nt * 2 + (c15 >> 3)) * 256 + n0 * 8 + (c15 & 7);
#pragma unroll
        for (int r = 0; r < 4; ++r) {
          int bb = mt * 16 + kgrp * 4 + r;
          acc[mt][nt][r] = gxd[((size_t)bb * S_ + s) * NG + grow];
        }
      }
    // wait for h_{s-1}: all 32 producer canaries >= s (no acquire, no cache inv)
    if (s > 0) {
      const unsigned int target = (unsigned int)s;
      while (true) {
        unsigned int v = __hip_atomic_load(&fl[(lane & 31) * 16], __ATOMIC_RELAXED, __HIP_MEMORY_SCOPE_AGENT);
        if (__all(v >= target)) break;
        __builtin_amdgcn_s_sleep(1);
      }
      asm volatile("" ::: "memory");  // compiler barrier: keep data loads below the poll
    }
    // load ALL h fragments as relaxed agent-scope u64 atomics (MALL-direct), then compute
    const unsigned long long* hr = (const unsigned long long*)(hb + ((s + 1) & 1) * 16384);
    unsigned long long hq[64];
#pragma unroll
    for (int ks = 0; ks < 8; ++ks) {
      const int cb = (ks * 4 + kgrp) << 7;  // producer chunk base in u64 (512 shorts / 4)
      const int a0o = cb + c15 * 2;
      const int a1o = cb + (c15 + 16) * 2;
      hq[ks * 8 + 0] = __hip_atomic_load(hr + a0o,          __ATOMIC_RELAXED, __HIP_MEMORY_SCOPE_AGENT);
      hq[ks * 8 + 1] = __hip_atomic_load(hr + a0o + 1,      __ATOMIC_RELAXED, __HIP_MEMORY_SCOPE_AGENT);
      hq[ks * 8 + 2] = __hip_atomic_load(hr + a1o,          __ATOMIC_RELAXED, __HIP_MEMORY_SCOPE_AGENT);
      hq[ks * 8 + 3] = __hip_atomic_load(hr + a1o + 1,      __ATOMIC_RELAXED, __HIP_MEMORY_SCOPE_AGENT);
      hq[ks * 8 + 4] = __hip_atomic_load(hr + a0o + 64,     __ATOMIC_RELAXED, __HIP_MEMORY_SCOPE_AGENT);
      hq[ks * 8 + 5] = __hip_atomic_load(hr + a0o + 64 + 1, __ATOMIC_RELAXED, __HIP_MEMORY_SCOPE_AGENT);
      hq[ks * 8 + 6] = __hip_atomic_load(hr + a1o + 64,     __ATOMIC_RELAXED, __HIP_MEMORY_SCOPE_AGENT);
      hq[ks * 8 + 7] = __hip_atomic_load(hr + a1o + 64 + 1, __ATOMIC_RELAXED, __HIP_MEMORY_SCOPE_AGENT);
    }
    // ks 0..7: A = h_hi, B regions 0 (W_hi) and 2 (W_lo)
#pragma unroll
    for (int ks = 0; ks < 8; ++ks) {
      U2 ua0, ua1;
      ua0.q[0] = hq[ks * 8 + 0]; ua0.q[1] = hq[ks * 8 + 1];
      ua1.q[0] = hq[ks * 8 + 2]; ua1.q[1] = hq[ks * 8 + 3];
      bf16x8 a0 = ua0.v, a1 = ua1.v;
      acc[0][0] = __builtin_amdgcn_mfma_f32_16x16x32_bf16(a0, bf[0][ks], acc[0][0], 0, 0, 0);
      acc[0][1] = __builtin_amdgcn_mfma_f32_16x16x32_bf16(a0, bf[1][ks], acc[0][1], 0, 0, 0);
      acc[1][0] = __builtin_amdgcn_mfma_f32_16x16x32_bf16(a1, bf[0][ks], acc[1][0], 0, 0, 0);
      acc[1][1] = __builtin_amdgcn_mfma_f32_16x16x32_bf16(a1, bf[1][ks], acc[1][1], 0, 0, 0);
      acc[0][0] = __builtin_amdgcn_mfma_f32_16x16x32_bf16(a0, bf[0][ks + 16], acc[0][0], 0, 0, 0);
      acc[0][1] = __builtin_amdgcn_mfma_f32_16x16x32_bf16(a0, bf[1][ks + 16], acc[0][1], 0, 0, 0);
      acc[1][0] = __builtin_amdgcn_mfma_f32_16x16x32_bf16(a1, bf[0][ks + 16], acc[1][0], 0, 0, 0);
      acc[1][1] = __builtin_amdgcn_mfma_f32_16x16x32_bf16(a1, bf[1][ks + 16], acc[1][1], 0, 0, 0);
    }
    // ks 8..15: A = h_lo, B region 1 (W_hi)
#pragma unroll
    for (int ks = 8; ks < 16; ++ks) {
      U2 ua0, ua1;
      ua0.q[0] = hq[(ks - 8) * 8 + 4]; ua0.q[1] = hq[(ks - 8) * 8 + 5];
      ua1.q[0] = hq[(ks - 8) * 8 + 6]; ua1.q[1] = hq[(ks - 8) * 8 + 7];
      bf16x8 a0 = ua0.v, a1 = ua1.v;
      acc[0][0] = __builtin_amdgcn_mfma_f32_16x16x32_bf16(a0, bf[0][ks], acc[0][0], 0, 0, 0);
      acc[0][1] = __builtin_amdgcn_mfma_f32_16x16x32_bf16(a0, bf[1][ks], acc[0][1], 0, 0, 0);
      acc[1][0] = __builtin_amdgcn_mfma_f32_16x16x32_bf16(a1, bf[0][ks], acc[1][0], 0, 0, 0);
      acc[1][1] = __builtin_amdgcn_mfma_f32_16x16x32_bf16(a1, bf[1][ks], acc[1][1], 0, 0, 0);
    }
    // epilogue: nt0 cols = [i(0..7), f(0..7)], nt1 cols = [g(0..7), o(0..7)]
    unsigned short* hw = hb + (s & 1) * 16384 + n0 * 512;  // this producer's exclusive 1KB
    float outv_[8];
    int   opos_[8];
#pragma unroll
    for (int mt = 0; mt < 2; ++mt)
#pragma unroll
      for (int r = 0; r < 4; ++r) {
        const int idx = mt * 4 + r;
        float x0 = acc[mt][0][r];
        float y0 = __shfl_xor(x0, 8);
        float x1 = acc[mt][1][r];
        float y1 = __shfl_xor(x1, 8);
        float iv = (lane & 8) ? y0 : x0;
        float fv = (lane & 8) ? x0 : y0;
        float gv = (lane & 8) ? y1 : x1;
        float ov = (lane & 8) ? x1 : y1;
        iv = sigm(iv); fv = sigm(fv); gv = tanh_(gv); ov = sigm(ov);
        bool act = (s < Le[idx]);
        float cn = fv * cst[idx] + iv * gv;
        float hn = ov * tanh_(cn);
        if (act) { cst[idx] = cn; hold[idx] = hn; }
        if (writer) {
          int bb = mt * 16 + kgrp * 4 + r;
          float hcur = hold[idx];
          unsigned short hi = f2bf(hcur);
          unsigned short lo = f2bf(hcur - bf2f(hi));
          __hip_atomic_store(&hw[bb * 8 + (lane & 7)], hi, __ATOMIC_RELAXED, __HIP_MEMORY_SCOPE_AGENT);
          __hip_atomic_store(&hw[256 + bb * 8 + (lane & 7)], lo, __ATOMIC_RELAXED, __HIP_MEMORY_SCOPE_AGENT);
          opos_[idx] = act ? (d == 0 ? s : (Le[idx] - 1 - s)) : s;
          outv_[idx] = act ? hn : 0.f;
        }
      }
    // release: h stores drained to MALL, then this producer's canary (relaxed, no RMW)
    asm volatile("s_waitcnt vmcnt(0)" ::: "memory");
    if (lane == 0)
      __hip_atomic_store(&fl[n0 * 16], (unsigned int)(s + 1), __ATOMIC_RELAXED, __HIP_MEMORY_SCOPE_AGENT);
    // out[] stores AFTER the flag — off the sync critical path, drain during next spin
    if (writer) {
#pragma unroll
      for (int mt = 0; mt < 2; ++mt)
#pragma unroll
        for (int r = 0; r < 4; ++r) {
          const int idx = mt * 4 + r;
          int bb = mt * 16 + kgrp * 4 + r;
          out[((size_t)bb * S_ + opos_[idx]) * H_ + d * HD_ + ue] = outv_[idx];
        }
    }
  }
}

// ---------------------------------------------------------------- dense (emissions)
__global__ __launch_bounds__(256) void dense_em(const float* __restrict__ h,
                                                const float* __restrict__ W,
                                                const float* __restrict__ bias,
                                                float* __restrict__ em) {
  const int tid = threadIdx.x;
  const int n = tid & 31, rg = tid >> 5;  // 8 row groups
  const int m0 = blockIdx.x * 16;
  const int r0 = m0 + rg, r1 = m0 + rg + 8;
  const float4* h0 = (const float4*)(h + (size_t)r0 * H_);
  const float4* h1 = (const float4*)(h + (size_t)r1 * H_);
  const float4* wn = (const float4*)(W + (size_t)n * H_);
  float a0 = 0.f, a1 = 0.f;
  for (int k4 = 0; k4 < 128; ++k4) {
    float4 w = wn[k4];
    float4 v0 = h0[k4];
    float4 v1 = h1[k4];
    a0 += v0.x * w.x + v0.y * w.y + v0.z * w.z + v0.w * w.w;
    a1 += v1.x * w.x + v1.y * w.y + v1.z * w.z + v1.w * w.w;
  }
  float bb = bias[n];
  em[(size_t)r0 * NL + n] = a0 + bb;
  em[(size_t)r1 * NL + n] = a1 + bb;
}

// ---------------------------------------------------------------- viterbi
__global__ __launch_bounds__(64) void viterbi(const float* __restrict__ em,
                                              const int* __restrict__ lens,
                                              const float* __restrict__ tr,
                                              const float* __restrict__ st,
                                              const float* __restrict__ et,
                                              float* __restrict__ tags,
                                              float* __restrict__ scores) {
  __shared__ unsigned char bp[512][32];
  const int b = blockIdx.x;
  const int lane = threadIdx.x;
  const int j = lane & 31;
  const int Lb = lens[b];
  const float* eb = em + (size_t)b * S_ * NL;
  float tc[32];
#pragma unroll
  for (int i = 0; i < 32; ++i) tc[i] = tr[i * 32 + j];
  float alpha = st[j] + eb[j];
  for (int t = 1; t < Lb; ++t) {
    float m = -3.4e38f;
    int mi = 0;
#pragma unroll
    for (int i = 0; i < 32; ++i) {
      float v = __shfl(alpha, i, 64) + tc[i];
      if (v > m) { m = v; mi = i; }   // strict > : first max wins (np.argmax)
    }
    if (lane < 32) bp[t][j] = (unsigned char)mi;
    alpha = m + eb[t * NL + j];
  }
  float fin = alpha + et[j];
  float m = -3.4e38f;
  int mi = 0;
#pragma unroll
  for (int i = 0; i < 32; ++i) {
    float v = __shfl(fin, i, 64);
    if (v > m) { m = v; mi = i; }
  }
  __syncthreads();  // bp visible to lane 0
  if (lane == 0) {
    scores[b] = m;
    int cur = mi;
    for (int t = Lb - 1; t >= 1; --t) {
      tags[(size_t)b * S_ + t] = (float)cur;
      cur = bp[t][cur];
    }
    tags[(size_t)b * S_] = (float)cur;
  }
  for (int t = Lb + lane; t < S_; t += 64) tags[(size_t)b * S_ + t] = 0.f;
}

// ---------------------------------------------------------------- launch
extern "C" void kernel_launch(void* const* d_in, const int* in_sizes, int n_in,
                              void* d_out, int out_size, void* d_ws, size_t ws_size,
                              hipStream_t stream) {
  const int*   x     = (const int*)d_in[0];
  const int*   xlen  = (const int*)d_in[1];
  const float* emb   = (const float*)d_in[2];
  const float* w_ih0 = (const float*)d_in[3];
  const float* w_hh0 = (const float*)d_in[4];
  const float* b_ih0 = (const float*)d_in[5];
  const float* b_hh0 = (const float*)d_in[6];
  const float* w_ih1 = (const float*)d_in[7];
  const float* w_hh1 = (const float*)d_in[8];
  const float* b_ih1 = (const float*)d_in[9];
  const float* b_hh1 = (const float*)d_in[10];
  const float* dw    = (const float*)d_in[11];
  const float* db    = (const float*)d_in[12];
  const float* tr    = (const float*)d_in[13];
  const float* st    = (const float*)d_in[14];
  const float* et    = (const float*)d_in[15];

  char* ws = (char*)d_ws;
  // ws layout (bytes): gx 128MB | out0 32MB | out1 32MB | Wp 6MB | hbuf 256KB (2 layers) | flags 8KB
  float*          gx    = (float*)(ws);
  float*          out0  = (float*)(ws + 134217728);
  float*          out1  = (float*)(ws + 167772160);
  unsigned short* Wp    = (unsigned short*)(ws + 201326592);
  unsigned short* hbuf  = (unsigned short*)(ws + 207618048);
  unsigned int*   flags = (unsigned int*)(ws + 207880192);  // = hbuf + 262144B (contiguous)

  float* emis   = (float*)d_out;          // [32][512][32]
  float* tags   = emis + 524288;          // [32][512]
  float* scores = tags + 16384;           // [32]

  // zero hbuf (2 layers x 128KB = 65536 u32) + flags (2 layers x 1024 u32) — contiguous
  init_zero<<<264, 256, 0, stream>>>((unsigned int*)hbuf, 67584);
  init_wperm<<<12288, 256, 0, stream>>>(w_hh0, w_hh1, Wp);

  // layer 0
  gemm_gx<256><<<dim3(8, 128, 2), 256, 0, stream>>>(emb, x, xlen, w_ih0, b_ih0, b_hh0, gx);
  lstm_rec<<<64, 64, 0, stream>>>(gx, Wp, xlen, hbuf, flags, out0);
  // layer 1
  gemm_gx<512><<<dim3(8, 128, 2), 256, 0, stream>>>(out0, nullptr, xlen, w_ih1, b_ih1, b_hh1, gx);
  lstm_rec<<<64, 64, 0, stream>>>(gx, Wp + 1572864, xlen, hbuf + 65536, flags + 1024, out1);
  // emissions + CRF decode
  dense_em<<<1024, 256, 0, stream>>>(out1, dw, db, emis);
  viterbi<<<32, 64, 0, stream>>>(emis, xlen, tr, st, et, tags, scores);
}